// Round 7
// baseline (229.752 us; speedup 1.0000x reference)
//
#include <hip/hip_runtime.h>

namespace {
constexpr int NB = 256, NN = 1024, DIN = 64, HID = 256, DOUT = 128;
constexpr int SPLIT = 2, CHUNK = NN / SPLIT;   // 512 elements per block
constexpr int MT = 64;                          // rows per tile

typedef __attribute__((ext_vector_type(8))) short bf16x8;
typedef __attribute__((ext_vector_type(4))) float f32x4;

// ws: pooled f32[NB*HID] (256KB), cnts i32[NB] (1KB), w1p bf16 (32KB), w2p bf16 (128KB)
constexpr size_t POOLED_OFF = 0;
constexpr size_t CNTS_OFF   = (size_t)NB * HID * 4;
constexpr size_t PW1_OFF    = CNTS_OFF + (size_t)NB * 4;
constexpr size_t PW2_OFF    = PW1_OFF + (size_t)DIN * HID * 2;
constexpr int ZERO_N = NB * HID + NB;           // pooled + cnts (0.f bits == 0)

__device__ inline unsigned short f2bf(float f) {   // RNE float->bf16
    union { float f; unsigned u; } v; v.f = f;
    unsigned r = v.u + 0x7FFF + ((v.u >> 16) & 1);
    return (unsigned short)(r >> 16);
}
__device__ inline unsigned pk2(float lo, float hi) {   // two f32 -> packed bf16x2
    return (unsigned)f2bf(lo) | ((unsigned)f2bf(hi) << 16);
}

// ---- kernel 0: zero pooled+cnts; pack W1/W2 to MFMA B-frag order, coalesced b128 stores ----
// B-frag (16x16x32): lane holds W[k0+(lane>>4)*8+j][n0+(lane&15)], j=0..7 contiguous.
// w1p shorts: u*8+j with u = (strip*2+kk)*64+lane ; w2p: u = (strip*8+kk)*64+lane
__global__ void prep(const float* __restrict__ pw1, const float* __restrict__ pw2,
                     float* __restrict__ zero_base,
                     unsigned short* __restrict__ w1p, unsigned short* __restrict__ w2p) {
    int i = blockIdx.x * 256 + threadIdx.x;            // 257 blocks -> 65792
    if (i < ZERO_N) zero_base[i] = 0.f;
    if (i < DIN * HID / 8) {                           // 2048 outputs
        int lane = i & 63, kk = (i >> 6) & 1, strip = i >> 7;
        int kbase = kk * 32 + ((lane >> 4) * 8);
        int n = strip * 16 + (lane & 15);
        const float* src = pw1 + (size_t)kbase * HID + n;
        float v[8];
#pragma unroll
        for (int j = 0; j < 8; ++j) v[j] = src[(size_t)j * HID];
        unsigned o[4] = {pk2(v[0],v[1]), pk2(v[2],v[3]), pk2(v[4],v[5]), pk2(v[6],v[7])};
        *(uint4*)(w1p + (size_t)i * 8) = *(const uint4*)o;
    }
    if (i < HID * HID / 8) {                           // 8192 outputs
        int lane = i & 63, kk = (i >> 6) & 7, strip = i >> 9;
        int kbase = kk * 32 + ((lane >> 4) * 8);
        int n = strip * 16 + (lane & 15);
        const float* src = pw2 + (size_t)kbase * HID + n;
        float v[8];
#pragma unroll
        for (int j = 0; j < 8; ++j) v[j] = src[(size_t)j * HID];
        unsigned o[4] = {pk2(v[0],v[1]), pk2(v[2],v[3]), pk2(v[4],v[5]), pk2(v[6],v[7])};
        *(uint4*)(w2p + (size_t)i * 8) = *(const uint4*)o;
    }
}

// ---- kernel 1: phi (2 bf16 MFMA layers, W in regs) + masked pool -> global atomics ----
// grid (NB, SPLIT) = 512 blocks (2/CU), 512 thr = 8 waves (4/SIMD). Wave wq owns cols wq*32..+31.
__launch_bounds__(512, 4)
__global__ void phi_pool(const float* __restrict__ x, const int* __restrict__ mask,
                         const float* __restrict__ pb1, const float* __restrict__ pb2,
                         const unsigned short* __restrict__ w1p,
                         const unsigned short* __restrict__ w2p,
                         float* __restrict__ pooled, int* __restrict__ cnts) {
    __shared__ unsigned short xs[2][MT * 64];   // 16 KB, XOR-swizzled, double-buffered
    __shared__ unsigned short h1s[MT * 256];    // 32 KB, XOR-swizzled
    __shared__ short vlist[CHUNK];              // 1 KB
    __shared__ int cnt_s;

    const int b = blockIdx.x, sp = blockIdx.y, t = threadIdx.x;
    const int lane = t & 63, wq = t >> 6;
    const int quad = lane >> 4, l15 = lane & 15;

    if (t == 0) cnt_s = 0;
    __syncthreads();
    {
        int n = sp * CHUNK + t;                 // 512 threads cover the 512-chunk
        if (mask[b * NN + n] != 0) { int i = atomicAdd(&cnt_s, 1); vlist[i] = (short)n; }
    }
    __syncthreads();
    const int cnt = cnt_s;
    if (t == 0) atomicAdd(&cnts[b], cnt);

    // W fragments -> registers (once per block)
    const uint4* w1q = (const uint4*)w1p;
    const uint4* w2q = (const uint4*)w2p;
    uint4 w1f[2][2], w2f[8][2];
#pragma unroll
    for (int j = 0; j < 2; ++j) {
        int strip = wq * 2 + j;
#pragma unroll
        for (int kk = 0; kk < 2; ++kk) w1f[kk][j] = w1q[(strip * 2 + kk) * 64 + lane];
#pragma unroll
        for (int kk = 0; kk < 8; ++kk) w2f[kk][j] = w2q[(strip * 8 + kk) * 64 + lane];
    }
    float bias1[2], bias2[2];
#pragma unroll
    for (int j = 0; j < 2; ++j) {
        int c = wq * 32 + j * 16 + l15;
        bias1[j] = pb1[c]; bias2[j] = pb2[c];
    }

    float pool[2] = {0.f, 0.f};
    const float* xb = x + (size_t)b * NN * DIN;
    const int gr = t >> 3, seg8 = t & 7;                 // gather row, 16B block
    const int xoff = gr * 64 + ((seg8 ^ (gr & 7)) << 3); // swizzled xs offset (shorts)

    // preload tile 0
    {
        float4 a0 = make_float4(0.f,0.f,0.f,0.f), a1 = a0;
        if (gr < min(MT, cnt)) {
            const float4* p = (const float4*)(xb + (size_t)vlist[gr] * DIN + seg8 * 8);
            a0 = p[0]; a1 = p[1];
        }
        unsigned o[4] = {pk2(a0.x,a0.y), pk2(a0.z,a0.w), pk2(a1.x,a1.y), pk2(a1.z,a1.w)};
        *(uint4*)&xs[0][xoff] = *(const uint4*)o;
    }

    int cur = 0;
    for (int base = 0; base < cnt; base += MT) {
        __syncthreads();                                  // xs[cur] visible, h1s readers done

        // layer 1: xs -> h1s (K=64)
        f32x4 acc[4][2];
#pragma unroll
        for (int f = 0; f < 4; ++f)
#pragma unroll
            for (int j = 0; j < 2; ++j) acc[f][j] = (f32x4){0.f,0.f,0.f,0.f};
#pragma unroll
        for (int kk = 0; kk < 2; ++kk) {
            bf16x8 a[4];
#pragma unroll
            for (int f = 0; f < 4; ++f)
                a[f] = *(const bf16x8*)&xs[cur][(f*16 + l15)*64 + (((kk*4 + quad) ^ (l15 & 7)) << 3)];
#pragma unroll
            for (int j = 0; j < 2; ++j) {
                bf16x8 bw = __builtin_bit_cast(bf16x8, w1f[kk][j]);
#pragma unroll
                for (int f = 0; f < 4; ++f)
                    acc[f][j] = __builtin_amdgcn_mfma_f32_16x16x32_bf16(a[f], bw, acc[f][j], 0, 0, 0);
            }
        }
#pragma unroll
        for (int f = 0; f < 4; ++f)
#pragma unroll
            for (int j = 0; j < 2; ++j) {
                int col = wq * 32 + j * 16 + l15, kb = col >> 3, cl = col & 7;
#pragma unroll
                for (int r = 0; r < 4; ++r) {
                    int row = f * 16 + quad * 4 + r;
                    float h = fmaxf(acc[f][j][r] + bias1[j], 0.f);
                    h1s[row * 256 + ((kb ^ (row & 7)) << 3) + cl] = f2bf(h);
                }
            }

        // prefetch next x tile into regs
        float4 n0 = make_float4(0.f,0.f,0.f,0.f), n1 = n0;
        const bool hn = (base + MT) < cnt;
        if (hn && gr < cnt - (base + MT)) {
            const float4* p = (const float4*)(xb + (size_t)vlist[base + MT + gr] * DIN + seg8 * 8);
            n0 = p[0]; n1 = p[1];
        }
        __syncthreads();                                  // h1s visible

        // layer 2: h1s -> pool (K=256), W2 from registers
        f32x4 acc2[4][2];
#pragma unroll
        for (int f = 0; f < 4; ++f)
#pragma unroll
            for (int j = 0; j < 2; ++j) acc2[f][j] = (f32x4){0.f,0.f,0.f,0.f};
#pragma unroll
        for (int kk = 0; kk < 8; ++kk) {
            bf16x8 a[4];
#pragma unroll
            for (int f = 0; f < 4; ++f)
                a[f] = *(const bf16x8*)&h1s[(f*16 + l15)*256 + (((kk*4 + quad) ^ (l15 & 7)) << 3)];
#pragma unroll
            for (int j = 0; j < 2; ++j) {
                bf16x8 bw = __builtin_bit_cast(bf16x8, w2f[kk][j]);
#pragma unroll
                for (int f = 0; f < 4; ++f)
                    acc2[f][j] = __builtin_amdgcn_mfma_f32_16x16x32_bf16(a[f], bw, acc2[f][j], 0, 0, 0);
            }
        }
#pragma unroll
        for (int f = 0; f < 4; ++f)
#pragma unroll
            for (int r = 0; r < 4; ++r) {
                bool v = (base + f * 16 + quad * 4 + r) < cnt;
#pragma unroll
                for (int j = 0; j < 2; ++j) {
                    float h = fmaxf(acc2[f][j][r] + bias2[j], 0.f);
                    pool[j] += v ? h : 0.f;
                }
            }

        if (hn) {
            unsigned o[4] = {pk2(n0.x,n0.y), pk2(n0.z,n0.w), pk2(n1.x,n1.y), pk2(n1.z,n1.w)};
            *(uint4*)&xs[cur ^ 1][xoff] = *(const uint4*)o;
        }
        cur ^= 1;
    }

    // cross-quad reduce; one atomic per col per wave (cols wave-disjoint)
#pragma unroll
    for (int j = 0; j < 2; ++j) {
        float v = pool[j];
        v += __shfl_xor(v, 16, 64);
        v += __shfl_xor(v, 32, 64);
        if (quad == 0) atomicAdd(&pooled[b * HID + wq * 32 + j * 16 + l15], v);
    }
}

// ---- kernel 2: folded pw3 + rho chain, fp32, coalesced float4 weights (verified in R4) ----
__device__ inline float4 dotseg(const float* __restrict__ buf, const float* __restrict__ W,
                                int c, int s) {
    const float4* W4 = (const float4*)W;       // rows of 64 float4 (N=256)
    float4 acc = make_float4(0.f, 0.f, 0.f, 0.f);
#pragma unroll 8
    for (int i = 0; i < 32; ++i) {
        int k = s * 32 + i;
        float bk = buf[k];
        float4 w = W4[(size_t)k * 64 + c];
        acc.x = fmaf(bk, w.x, acc.x);
        acc.y = fmaf(bk, w.y, acc.y);
        acc.z = fmaf(bk, w.z, acc.z);
        acc.w = fmaf(bk, w.w, acc.w);
    }
    return acc;
}

__launch_bounds__(512, 2)
__global__ void rho(const float* __restrict__ pooled, const int* __restrict__ cnts,
                    const float* __restrict__ pw3, const float* __restrict__ pb3,
                    const float* __restrict__ rw1, const float* __restrict__ rb1,
                    const float* __restrict__ rw2, const float* __restrict__ rb2,
                    const float* __restrict__ rw3, const float* __restrict__ rb3,
                    float* __restrict__ out) {
    __shared__ float bufA[HID], bufB[HID];
    __shared__ float part[8][HID];
    const int b = blockIdx.x, t = threadIdx.x;
    const int c = t & 63, s = t >> 6;
    const int cnt = cnts[b];
    if (t < HID) bufA[t] = pooled[b * HID + t];
    __syncthreads();

    {   // folded phi-3
        float4 p = dotseg(bufA, pw3, c, s);
        ((float4*)part[s])[c] = p;
        __syncthreads();
        if (t < HID) {
            float v = (float)cnt * pb3[t];
#pragma unroll
            for (int g = 0; g < 8; ++g) v += part[g][t];
            bufB[t] = v;
        }
        __syncthreads();
    }
    {   // rho-1
        float4 p = dotseg(bufB, rw1, c, s);
        ((float4*)part[s])[c] = p;
        __syncthreads();
        if (t < HID) {
            float v = rb1[t];
#pragma unroll
            for (int g = 0; g < 8; ++g) v += part[g][t];
            bufA[t] = fmaxf(v, 0.f);
        }
        __syncthreads();
    }
    {   // rho-2
        float4 p = dotseg(bufA, rw2, c, s);
        ((float4*)part[s])[c] = p;
        __syncthreads();
        if (t < HID) {
            float v = rb2[t];
#pragma unroll
            for (int g = 0; g < 8; ++g) v += part[g][t];
            bufB[t] = fmaxf(v, 0.f);
        }
        __syncthreads();
    }
    {   // rho-3, N=128
        const int c4 = t & 31, s4 = t >> 5;
        const float4* W4 = (const float4*)rw3;
        float4 acc = make_float4(0.f, 0.f, 0.f, 0.f);
#pragma unroll 8
        for (int i = 0; i < 16; ++i) {
            int k = s4 * 16 + i;
            float bk = bufB[k];
            float4 w = W4[(size_t)k * 32 + c4];
            acc.x = fmaf(bk, w.x, acc.x);
            acc.y = fmaf(bk, w.y, acc.y);
            acc.z = fmaf(bk, w.z, acc.z);
            acc.w = fmaf(bk, w.w, acc.w);
        }
        float* part2 = &part[0][0];             // reuse as [16][128]
        ((float4*)(part2 + s4 * DOUT))[c4] = acc;
        __syncthreads();
        if (t < DOUT) {
            float v = rb3[t];
#pragma unroll
            for (int g = 0; g < 16; ++g) v += part2[g * DOUT + t];
            out[b * DOUT + t] = (cnt > 0) ? v : 0.f;
        }
    }
}
} // namespace

extern "C" void kernel_launch(void* const* d_in, const int* in_sizes, int n_in,
                              void* d_out, int out_size, void* d_ws, size_t ws_size,
                              hipStream_t stream) {
    const float* x    = (const float*)d_in[0];
    const int*   mask = (const int*)  d_in[1];
    const float* pw1  = (const float*)d_in[2];
    const float* pb1  = (const float*)d_in[3];
    const float* pw2  = (const float*)d_in[4];
    const float* pb2  = (const float*)d_in[5];
    const float* pw3  = (const float*)d_in[6];
    const float* pb3  = (const float*)d_in[7];
    const float* rw1  = (const float*)d_in[8];
    const float* rb1  = (const float*)d_in[9];
    const float* rw2  = (const float*)d_in[10];
    const float* rb2  = (const float*)d_in[11];
    const float* rw3  = (const float*)d_in[12];
    const float* rb3  = (const float*)d_in[13];
    float* out = (float*)d_out;

    float* pooled       = (float*)((char*)d_ws + POOLED_OFF);
    int*   cnts         = (int*)  ((char*)d_ws + CNTS_OFF);
    unsigned short* w1p = (unsigned short*)((char*)d_ws + PW1_OFF);
    unsigned short* w2p = (unsigned short*)((char*)d_ws + PW2_OFF);

    prep<<<dim3(257), dim3(256), 0, stream>>>(pw1, pw2, (float*)d_ws, w1p, w2p);
    phi_pool<<<dim3(NB, SPLIT), dim3(512), 0, stream>>>(x, mask, pb1, pb2, w1p, w2p, pooled, cnts);
    rho<<<dim3(NB), dim3(512), 0, stream>>>(pooled, cnts, pw3, pb3,
                                            rw1, rb1, rw2, rb2, rw3, rb3, out);
}

// Round 8
// 152.672 us; speedup vs baseline: 1.5049x; 1.5049x over previous
//
#include <hip/hip_runtime.h>

namespace {
constexpr int NB = 256, NN = 1024, DIN = 64, HID = 256, DOUT = 128;
constexpr int SPLIT = 2, CHUNK = NN / SPLIT;   // 512 elements per block
constexpr int MT = 64;                          // rows per tile

typedef __attribute__((ext_vector_type(8))) short bf16x8;
typedef __attribute__((ext_vector_type(4))) float f32x4;

// ws: pooled f32[NB*HID] (256KB), cnts i32[NB] (1KB), w1p bf16 (32KB), w2p bf16 (128KB)
constexpr size_t POOLED_OFF = 0;
constexpr size_t CNTS_OFF   = (size_t)NB * HID * 4;
constexpr size_t PW1_OFF    = CNTS_OFF + (size_t)NB * 4;
constexpr size_t PW2_OFF    = PW1_OFF + (size_t)DIN * HID * 2;
constexpr int ZERO_N = NB * HID + NB;           // pooled + cnts (0.f bits == 0)

__device__ inline unsigned short f2bf(float f) {   // RNE float->bf16
    union { float f; unsigned u; } v; v.f = f;
    unsigned r = v.u + 0x7FFF + ((v.u >> 16) & 1);
    return (unsigned short)(r >> 16);
}
__device__ inline unsigned pk2(float lo, float hi) {   // two f32 -> packed bf16x2
    return (unsigned)f2bf(lo) | ((unsigned)f2bf(hi) << 16);
}

// ---- kernel 0: zero pooled+cnts; pack W1/W2 to MFMA B-frag order, coalesced b128 stores ----
// B-frag (16x16x32): lane holds W[k0+(lane>>4)*8+j][n0+(lane&15)], j=0..7 contiguous.
__global__ void prep(const float* __restrict__ pw1, const float* __restrict__ pw2,
                     float* __restrict__ zero_base,
                     unsigned short* __restrict__ w1p, unsigned short* __restrict__ w2p) {
    int i = blockIdx.x * 256 + threadIdx.x;            // 257 blocks -> 65792
    if (i < ZERO_N) zero_base[i] = 0.f;
    if (i < DIN * HID / 8) {                           // 2048 outputs
        int lane = i & 63, kk = (i >> 6) & 1, strip = i >> 7;
        int kbase = kk * 32 + ((lane >> 4) * 8);
        int n = strip * 16 + (lane & 15);
        const float* src = pw1 + (size_t)kbase * HID + n;
        float v[8];
#pragma unroll
        for (int j = 0; j < 8; ++j) v[j] = src[(size_t)j * HID];
        unsigned o[4] = {pk2(v[0],v[1]), pk2(v[2],v[3]), pk2(v[4],v[5]), pk2(v[6],v[7])};
        *(uint4*)(w1p + (size_t)i * 8) = *(const uint4*)o;
    }
    if (i < HID * HID / 8) {                           // 8192 outputs
        int lane = i & 63, kk = (i >> 6) & 7, strip = i >> 9;
        int kbase = kk * 32 + ((lane >> 4) * 8);
        int n = strip * 16 + (lane & 15);
        const float* src = pw2 + (size_t)kbase * HID + n;
        float v[8];
#pragma unroll
        for (int j = 0; j < 8; ++j) v[j] = src[(size_t)j * HID];
        unsigned o[4] = {pk2(v[0],v[1]), pk2(v[2],v[3]), pk2(v[4],v[5]), pk2(v[6],v[7])};
        *(uint4*)(w2p + (size_t)i * 8) = *(const uint4*)o;
    }
}

// ---- kernel 1: phi (2 bf16 MFMA layers) + masked pool -> global atomics ----
// grid (NB,2) = 512 blocks, 512 thr = 8 waves. Wave wq owns cols wq*32..+31.
// W2 frags resident in regs (64 VGPR); W1 frags streamed from L2 per tile.
__launch_bounds__(512, 2)
__global__ void phi_pool(const float* __restrict__ x, const int* __restrict__ mask,
                         const float* __restrict__ pb1, const float* __restrict__ pb2,
                         const unsigned short* __restrict__ w1p,
                         const unsigned short* __restrict__ w2p,
                         float* __restrict__ pooled, int* __restrict__ cnts) {
    __shared__ unsigned short xs[2][MT * 64];   // 16 KB, XOR-swizzled, double-buffered
    __shared__ unsigned short h1s[MT * 256];    // 32 KB, XOR-swizzled
    __shared__ short vlist[CHUNK];              // 1 KB
    __shared__ int cnt_s;

    const int b = blockIdx.x, sp = blockIdx.y, t = threadIdx.x;
    const int lane = t & 63, wq = t >> 6;
    const int quad = lane >> 4, l15 = lane & 15;

    if (t == 0) cnt_s = 0;
    __syncthreads();
    {
        int n = sp * CHUNK + t;
        if (mask[b * NN + n] != 0) { int i = atomicAdd(&cnt_s, 1); vlist[i] = (short)n; }
    }
    __syncthreads();
    const int cnt = cnt_s;
    if (t == 0) atomicAdd(&cnts[b], cnt);

    const uint4* w1q = (const uint4*)w1p;
    const uint4* w2q = (const uint4*)w2p;
    // W2 fragments -> registers (once per block)
    uint4 w2f[8][2];
#pragma unroll
    for (int j = 0; j < 2; ++j) {
        int strip = wq * 2 + j;
#pragma unroll
        for (int kk = 0; kk < 8; ++kk) w2f[kk][j] = w2q[(strip * 8 + kk) * 64 + lane];
    }
    float bias1[2], bias2[2];
#pragma unroll
    for (int j = 0; j < 2; ++j) {
        int c = wq * 32 + j * 16 + l15;
        bias1[j] = pb1[c]; bias2[j] = pb2[c];
    }

    float pool[2] = {0.f, 0.f};
    const float* xb = x + (size_t)b * NN * DIN;
    const int gr = t >> 3, seg8 = t & 7;                 // gather row, 16B block
    const int xoff = gr * 64 + ((seg8 ^ (gr & 7)) << 3); // swizzled xs offset (shorts)

    // preload tile 0
    {
        float4 a0 = make_float4(0.f,0.f,0.f,0.f), a1 = a0;
        if (gr < min(MT, cnt)) {
            const float4* p = (const float4*)(xb + (size_t)vlist[gr] * DIN + seg8 * 8);
            a0 = p[0]; a1 = p[1];
        }
        unsigned o[4] = {pk2(a0.x,a0.y), pk2(a0.z,a0.w), pk2(a1.x,a1.y), pk2(a1.z,a1.w)};
        *(uint4*)&xs[0][xoff] = *(const uint4*)o;
    }

    int cur = 0;
    for (int base = 0; base < cnt; base += MT) {
        // W1 fragments for this wave, streamed (issued before the barrier wait drains)
        uint4 w1t[2][2];
#pragma unroll
        for (int j = 0; j < 2; ++j)
#pragma unroll
            for (int kk = 0; kk < 2; ++kk)
                w1t[kk][j] = w1q[((wq * 2 + j) * 2 + kk) * 64 + lane];

        __syncthreads();                                  // xs[cur] visible, h1s readers done

        // layer 1: xs -> h1s (K=64)
        f32x4 acc[4][2];
#pragma unroll
        for (int f = 0; f < 4; ++f)
#pragma unroll
            for (int j = 0; j < 2; ++j) acc[f][j] = (f32x4){0.f,0.f,0.f,0.f};
#pragma unroll
        for (int kk = 0; kk < 2; ++kk) {
            bf16x8 a[4];
#pragma unroll
            for (int f = 0; f < 4; ++f)
                a[f] = *(const bf16x8*)&xs[cur][(f*16 + l15)*64 + (((kk*4 + quad) ^ (l15 & 7)) << 3)];
#pragma unroll
            for (int j = 0; j < 2; ++j) {
                bf16x8 bw = __builtin_bit_cast(bf16x8, w1t[kk][j]);
#pragma unroll
                for (int f = 0; f < 4; ++f)
                    acc[f][j] = __builtin_amdgcn_mfma_f32_16x16x32_bf16(a[f], bw, acc[f][j], 0, 0, 0);
            }
        }
#pragma unroll
        for (int f = 0; f < 4; ++f)
#pragma unroll
            for (int j = 0; j < 2; ++j) {
                int col = wq * 32 + j * 16 + l15, kb = col >> 3, cl = col & 7;
#pragma unroll
                for (int r = 0; r < 4; ++r) {
                    int row = f * 16 + quad * 4 + r;
                    float h = fmaxf(acc[f][j][r] + bias1[j], 0.f);
                    h1s[row * 256 + ((kb ^ (row & 7)) << 3) + cl] = f2bf(h);
                }
            }

        // prefetch next x tile into regs
        float4 n0 = make_float4(0.f,0.f,0.f,0.f), n1 = n0;
        const bool hn = (base + MT) < cnt;
        if (hn && gr < cnt - (base + MT)) {
            const float4* p = (const float4*)(xb + (size_t)vlist[base + MT + gr] * DIN + seg8 * 8);
            n0 = p[0]; n1 = p[1];
        }
        __syncthreads();                                  // h1s visible

        // layer 2: h1s -> pool (K=256), W2 from registers
        f32x4 acc2[4][2];
#pragma unroll
        for (int f = 0; f < 4; ++f)
#pragma unroll
            for (int j = 0; j < 2; ++j) acc2[f][j] = (f32x4){0.f,0.f,0.f,0.f};
#pragma unroll
        for (int kk = 0; kk < 8; ++kk) {
            bf16x8 a[4];
#pragma unroll
            for (int f = 0; f < 4; ++f)
                a[f] = *(const bf16x8*)&h1s[(f*16 + l15)*256 + (((kk*4 + quad) ^ (l15 & 7)) << 3)];
#pragma unroll
            for (int j = 0; j < 2; ++j) {
                bf16x8 bw = __builtin_bit_cast(bf16x8, w2f[kk][j]);
#pragma unroll
                for (int f = 0; f < 4; ++f)
                    acc2[f][j] = __builtin_amdgcn_mfma_f32_16x16x32_bf16(a[f], bw, acc2[f][j], 0, 0, 0);
            }
        }
        // pool epilogue: full tiles unpredicated; only the last partial tile predicates
        if (cnt - base >= MT) {
#pragma unroll
            for (int f = 0; f < 4; ++f)
#pragma unroll
                for (int r = 0; r < 4; ++r)
#pragma unroll
                    for (int j = 0; j < 2; ++j)
                        pool[j] += fmaxf(acc2[f][j][r] + bias2[j], 0.f);
        } else {
#pragma unroll
            for (int f = 0; f < 4; ++f)
#pragma unroll
                for (int r = 0; r < 4; ++r) {
                    bool v = (base + f * 16 + quad * 4 + r) < cnt;
#pragma unroll
                    for (int j = 0; j < 2; ++j) {
                        float h = fmaxf(acc2[f][j][r] + bias2[j], 0.f);
                        pool[j] += v ? h : 0.f;
                    }
                }
        }

        if (hn) {
            unsigned o[4] = {pk2(n0.x,n0.y), pk2(n0.z,n0.w), pk2(n1.x,n1.y), pk2(n1.z,n1.w)};
            *(uint4*)&xs[cur ^ 1][xoff] = *(const uint4*)o;
        }
        cur ^= 1;
    }

    // cross-quad reduce; one atomic per col per wave (cols wave-disjoint)
#pragma unroll
    for (int j = 0; j < 2; ++j) {
        float v = pool[j];
        v += __shfl_xor(v, 16, 64);
        v += __shfl_xor(v, 32, 64);
        if (quad == 0) atomicAdd(&pooled[b * HID + wq * 32 + j * 16 + l15], v);
    }
}

// ---- kernel 2: folded pw3 + rho chain, fp32, coalesced float4 weights ----
__device__ inline float4 dotseg(const float* __restrict__ buf, const float* __restrict__ W,
                                int c, int s) {
    const float4* W4 = (const float4*)W;       // rows of 64 float4 (N=256)
    float4 acc = make_float4(0.f, 0.f, 0.f, 0.f);
#pragma unroll 8
    for (int i = 0; i < 32; ++i) {
        int k = s * 32 + i;
        float bk = buf[k];
        float4 w = W4[(size_t)k * 64 + c];
        acc.x = fmaf(bk, w.x, acc.x);
        acc.y = fmaf(bk, w.y, acc.y);
        acc.z = fmaf(bk, w.z, acc.z);
        acc.w = fmaf(bk, w.w, acc.w);
    }
    return acc;
}

__launch_bounds__(512, 2)
__global__ void rho(const float* __restrict__ pooled, const int* __restrict__ cnts,
                    const float* __restrict__ pw3, const float* __restrict__ pb3,
                    const float* __restrict__ rw1, const float* __restrict__ rb1,
                    const float* __restrict__ rw2, const float* __restrict__ rb2,
                    const float* __restrict__ rw3, const float* __restrict__ rb3,
                    float* __restrict__ out) {
    __shared__ float bufA[HID], bufB[HID];
    __shared__ float part[8][HID];
    const int b = blockIdx.x, t = threadIdx.x;
    const int c = t & 63, s = t >> 6;
    const int cnt = cnts[b];
    if (t < HID) bufA[t] = pooled[b * HID + t];
    __syncthreads();

    {   // folded phi-3
        float4 p = dotseg(bufA, pw3, c, s);
        ((float4*)part[s])[c] = p;
        __syncthreads();
        if (t < HID) {
            float v = (float)cnt * pb3[t];
#pragma unroll
            for (int g = 0; g < 8; ++g) v += part[g][t];
            bufB[t] = v;
        }
        __syncthreads();
    }
    {   // rho-1
        float4 p = dotseg(bufB, rw1, c, s);
        ((float4*)part[s])[c] = p;
        __syncthreads();
        if (t < HID) {
            float v = rb1[t];
#pragma unroll
            for (int g = 0; g < 8; ++g) v += part[g][t];
            bufA[t] = fmaxf(v, 0.f);
        }
        __syncthreads();
    }
    {   // rho-2
        float4 p = dotseg(bufA, rw2, c, s);
        ((float4*)part[s])[c] = p;
        __syncthreads();
        if (t < HID) {
            float v = rb2[t];
#pragma unroll
            for (int g = 0; g < 8; ++g) v += part[g][t];
            bufB[t] = fmaxf(v, 0.f);
        }
        __syncthreads();
    }
    {   // rho-3, N=128
        const int c4 = t & 31, s4 = t >> 5;
        const float4* W4 = (const float4*)rw3;
        float4 acc = make_float4(0.f, 0.f, 0.f, 0.f);
#pragma unroll 8
        for (int i = 0; i < 16; ++i) {
            int k = s4 * 16 + i;
            float bk = bufB[k];
            float4 w = W4[(size_t)k * 32 + c4];
            acc.x = fmaf(bk, w.x, acc.x);
            acc.y = fmaf(bk, w.y, acc.y);
            acc.z = fmaf(bk, w.z, acc.z);
            acc.w = fmaf(bk, w.w, acc.w);
        }
        float* part2 = &part[0][0];             // reuse as [16][128]
        ((float4*)(part2 + s4 * DOUT))[c4] = acc;
        __syncthreads();
        if (t < DOUT) {
            float v = rb3[t];
#pragma unroll
            for (int g = 0; g < 16; ++g) v += part2[g * DOUT + t];
            out[b * DOUT + t] = (cnt > 0) ? v : 0.f;
        }
    }
}
} // namespace

extern "C" void kernel_launch(void* const* d_in, const int* in_sizes, int n_in,
                              void* d_out, int out_size, void* d_ws, size_t ws_size,
                              hipStream_t stream) {
    const float* x    = (const float*)d_in[0];
    const int*   mask = (const int*)  d_in[1];
    const float* pw1  = (const float*)d_in[2];
    const float* pb1  = (const float*)d_in[3];
    const float* pw2  = (const float*)d_in[4];
    const float* pb2  = (const float*)d_in[5];
    const float* pw3  = (const float*)d_in[6];
    const float* pb3  = (const float*)d_in[7];
    const float* rw1  = (const float*)d_in[8];
    const float* rb1  = (const float*)d_in[9];
    const float* rw2  = (const float*)d_in[10];
    const float* rb2  = (const float*)d_in[11];
    const float* rw3  = (const float*)d_in[12];
    const float* rb3  = (const float*)d_in[13];
    float* out = (float*)d_out;

    float* pooled       = (float*)((char*)d_ws + POOLED_OFF);
    int*   cnts         = (int*)  ((char*)d_ws + CNTS_OFF);
    unsigned short* w1p = (unsigned short*)((char*)d_ws + PW1_OFF);
    unsigned short* w2p = (unsigned short*)((char*)d_ws + PW2_OFF);

    prep<<<dim3(257), dim3(256), 0, stream>>>(pw1, pw2, (float*)d_ws, w1p, w2p);
    phi_pool<<<dim3(NB, SPLIT), dim3(512), 0, stream>>>(x, mask, pb1, pb2, w1p, w2p, pooled, cnts);
    rho<<<dim3(NB), dim3(512), 0, stream>>>(pooled, cnts, pw3, pb3,
                                            rw1, rb1, rw2, rb2, rw3, rb3, out);
}